// Round 6
// baseline (81.253 us; speedup 1.0000x reference)
//
#include <hip/hip_runtime.h>

// Problem constants (match reference)
#define NB 8
#define NT 8
#define NO 25
#define NC 3
#define NH 192
#define NW 640
#define NP 16
#define ND 768
#define NGH 12
#define NGW 2
#define NKP (NB*NT*NO)   // 1600 keypoints
#define NK (NC*NP*NP)    // 768 (GEMM K)
#define NTASK (NKP*NC)   // 4800 pool tasks
#define NCVW ((NK*ND)/(256*4))  // 576 convw blocks (float4 per thread)

#define S_STRIDE 42      // bf16 footprint row stride in shorts (even: u32-aligned writes)

typedef __attribute__((ext_vector_type(4))) float  f32x4;
typedef __attribute__((ext_vector_type(8))) short  bf16x8;

static __device__ __forceinline__ unsigned short f2bf(float f) {
  union { float f; unsigned u; } x; x.f = f;
  unsigned r = x.u + 0x7FFFu + ((x.u >> 16) & 1u);   // round-to-nearest-even
  return (unsigned short)(r >> 16);
}
static __device__ __forceinline__ float bf2f(unsigned short s) {
  union { unsigned u; float f; } x; x.u = ((unsigned)s) << 16;
  return x.f;
}

// ---------------------------------------------------------------------------
// Kernel 1 (fused): blocks [0,NCVW) convert conv_w f32->bf16;
// blocks [NCVW, NCVW+NTASK) do ROI-align pooling, one per (keypoint,channel).
// Footprint staged in LDS as bf16 (16.1 KB) -> 8 blocks/CU resident (wave cap),
// maximizing outstanding cold-HBM fetches. Register staging: all <=8 footprint
// float4 loads issued together, converted to bf16 on the LDS write.
// ---------------------------------------------------------------------------
__global__ __launch_bounds__(256) void pool_convw_kernel(
    const float* __restrict__ features,   // [B][C][T][H][W] f32
    const float* __restrict__ keypoints,  // [N][3] (kx, ky, kr)
    const float* __restrict__ conv_w,     // [768][768] f32
    unsigned short* __restrict__ pooled,  // [N][768] bf16
    unsigned short* __restrict__ wbf)     // [768][768] bf16
{
  __shared__ unsigned short S[NH * S_STRIDE];   // 192*42*2 = 16128 B

  const int bid = blockIdx.x;
  const int tid = threadIdx.x;

  if (bid < NCVW) {                       // ---- conv_w convert path ----
    const int i = bid * 256 + tid;        // float4 index
    const float4 v = reinterpret_cast<const float4*>(conv_w)[i];
    ushort4 o;
    o.x = f2bf(v.x); o.y = f2bf(v.y); o.z = f2bf(v.z); o.w = f2bf(v.w);
    reinterpret_cast<ushort4*>(wbf)[i] = o;
    return;                               // no barrier on this path (block-uniform)
  }

  // ---- pooling path ----
  // XCD-chunked swizzle over 4800 tasks (4800 = 8*600; NCVW = 576 = 72*8
  // keeps the blockIdx->XCD phase aligned)
  const int rb = bid - NCVW;
  const int t  = (rb & 7) * (NTASK / 8) + (rb >> 3);
  const int n  = t / 3;
  const int ch = t - 3 * n;

  const float kx = keypoints[n * 3 + 0];
  const float ky = keypoints[n * 3 + 1];
  const float kr = keypoints[n * 3 + 2];

  // Boxes exactly as reference (by2 uses kx — reference quirk, keep it)
  const float bx1 = fmaxf(kx - kr, 0.0f);
  const float by1 = fmaxf(ky - kr, 0.0f);
  const float bx2 = fminf(kx + kr, (float)NW);
  const float by2 = fminf(kx + kr, (float)NH);

  const float start_h = by1 - 0.5f;
  const float start_w = bx1 - 0.5f;
  const float bin_h = (by2 - by1) * (1.0f / (float)NP);
  const float bin_w = (bx2 - bx1) * (1.0f / (float)NP);
  const int gh = (int)ceilf(bin_h);       // == ceil(roi_h / P), 1..12
  const int gw = (int)ceilf(bin_w);       // 1..2
  const float ghf = (float)max(gh, 1);
  const float gwf = (float)max(gw, 1);
  const float inv_count = 1.0f / (float)max(gh * gw, 1);
  const float sub_h = bin_h / ghf;        // sub-sample spacing
  const float sub_w = bin_w / gwf;

  // --- footprint extent (block-uniform; samples monotonic in bin,g) ---
  const float cy_min = start_h + 0.5f * sub_h;
  const float cy_max = start_h + 15.0f * bin_h + ((float)(gh - 1) + 0.5f) * sub_h;
  const float cx_min = start_w + 0.5f * sub_w;
  const float cx_max = start_w + 15.0f * bin_w + ((float)(gw - 1) + 0.5f) * sub_w;
  const int rmin = (int)floorf(fminf(fmaxf(cy_min, 0.0f), (float)(NH - 1)));
  const int rmax = min((int)floorf(fminf(fmaxf(cy_max, 0.0f), (float)(NH - 1))) + 1, NH - 1);
  const int cmin = (int)floorf(fminf(fmaxf(cx_min, 0.0f), (float)(NW - 1)));
  const int cmax = min((int)floorf(fminf(fmaxf(cx_max, 0.0f), (float)(NW - 1))) + 1, NW - 1);
  const int nrows = rmax - rmin + 1;          // <= 192
  const int cmin_al = cmin & ~3;              // 4-aligned for float4 loads
  const int nq = ((cmax - cmin_al) >> 2) + 1; // float4 groups per row, <= 10
  const int tot = nrows * nq;                 // <= 1920
  const float inv_nq = 1.0f / (float)nq;

  const int img  = n / NO;                    // b*T + t
  const int bb   = img / NT;
  const int timg = img - bb * NT;
  const float* __restrict__ src =
      features + (size_t)((bb * NC + ch) * NT + timg) * (NH * NW);

  // --- register staging: up to 8 predicated float4 loads, all independent ---
  float4 v0, v1, v2, v3, v4, v5, v6, v7;
  int ro0, ro1, ro2, ro3, ro4, ro5, ro6, ro7;   // LDS short offset, -1 = skip

#define STAGE_LOAD(Q, V, RO)                                                 \
  {                                                                          \
    const int e = tid + (Q << 8);                                            \
    if (e < tot) {                                                           \
      const int r  = (int)(((float)e + 0.5f) * inv_nq);                      \
      const int c4 = (e - r * nq) << 2;                                      \
      const int gc = cmin_al + c4;                                           \
      const float* p = src + (size_t)(rmin + r) * NW + gc;                   \
      if (gc + 3 < NW) { V = *reinterpret_cast<const float4*>(p); }          \
      else { V.x = p[0]; V.y = p[min(1, NW - 1 - gc)];                       \
             V.z = p[min(2, NW - 1 - gc)]; V.w = p[min(3, NW - 1 - gc)]; }   \
      RO = r * S_STRIDE + c4;                                                \
    } else { RO = -1; }                                                      \
  }

  STAGE_LOAD(0, v0, ro0) STAGE_LOAD(1, v1, ro1) STAGE_LOAD(2, v2, ro2)
  STAGE_LOAD(3, v3, ro3) STAGE_LOAD(4, v4, ro4) STAGE_LOAD(5, v5, ro5)
  STAGE_LOAD(6, v6, ro6) STAGE_LOAD(7, v7, ro7)
#undef STAGE_LOAD

  // bf16-pack on write: 2 x u32 per float4 (RO even -> u32-aligned)
#define STAGE_WRITE(V, RO)                                                   \
  if (RO >= 0) {                                                             \
    const unsigned lo = (unsigned)f2bf(V.x) | ((unsigned)f2bf(V.y) << 16);   \
    const unsigned hi = (unsigned)f2bf(V.z) | ((unsigned)f2bf(V.w) << 16);   \
    unsigned* s = reinterpret_cast<unsigned*>(&S[RO]);                       \
    s[0] = lo; s[1] = hi;                                                    \
  }

  STAGE_WRITE(v0, ro0) STAGE_WRITE(v1, ro1) STAGE_WRITE(v2, ro2)
  STAGE_WRITE(v3, ro3) STAGE_WRITE(v4, ro4) STAGE_WRITE(v5, ro5)
  STAGE_WRITE(v6, ro6) STAGE_WRITE(v7, ro7)
#undef STAGE_WRITE

  // zero pad column (first column beyond staged region): the x0+1 read hits
  // it only when lx==0 (weight 0) — keep it finite, not stale-LDS bits.
  if (tid < nrows) S[tid * S_STRIDE + (nq << 2)] = 0;

  __syncthreads();

  // --- bilinear sampling (per-thread coords; reference formula order) ---
  const int i = tid >> 4;
  const int j = tid & 15;

  float lxv[NGW]; int cxv[NGW];
#pragma unroll
  for (int gx = 0; gx < NGW; ++gx) {
    const float c = start_w + (float)j * bin_w + ((float)gx + 0.5f) * sub_w;
    const float cc = fminf(fmaxf(c, 0.0f), (float)(NW - 1));
    const int x0 = (int)floorf(cc);
    lxv[gx] = cc - (float)x0;
    cxv[gx] = x0 - cmin_al;    // x1 = x0+1 implicit (pad col is zero, weight 0)
  }

  float acc = 0.0f;
#pragma unroll
  for (int gy = 0; gy < NGH; ++gy) {
    if (gy >= gh) break;               // block-uniform bound
    const float c = start_h + (float)i * bin_h + ((float)gy + 0.5f) * sub_h;
    const float cc = fminf(fmaxf(c, 0.0f), (float)(NH - 1));
    const int y0 = (int)floorf(cc);
    const float ly = cc - (float)y0;
    const float hy = 1.0f - ly;
    const int ry0 = (y0 - rmin) * S_STRIDE;
    const int ry1 = (min(y0 + 1, NH - 1) - rmin) * S_STRIDE;
#pragma unroll
    for (int gx = 0; gx < NGW; ++gx) {
      if (gx >= gw) break;             // block-uniform bound
      const float lx = lxv[gx];
      const float hx = 1.0f - lx;
      const int c0 = cxv[gx];
      const float s00 = bf2f(S[ry0 + c0]);
      const float s01 = bf2f(S[ry0 + c0 + 1]);
      const float s10 = bf2f(S[ry1 + c0]);
      const float s11 = bf2f(S[ry1 + c0 + 1]);
      acc += hy * (hx * s00 + lx * s01) + ly * (hx * s10 + lx * s11);
    }
  }
  pooled[(size_t)n * NK + ch * (NP * NP) + tid] = f2bf(acc * inv_count);
}

// ---------------------------------------------------------------------------
// Kernel 2: bf16 MFMA GEMM  out[1600][768] = A[1600][768] . Bw[768][768]^T + b
// BM=BN=64, BK=64, grid 25x12=300 blocks, 4 waves (2x2), wave tile 32x32.
// Double-buffered LDS, 2-phase prefetch, XOR-swizzle via pre-swizzled source.
// (identical to round 4)
// ---------------------------------------------------------------------------
#define BM 64
#define BN 64
#define BK 64

static __device__ __forceinline__ void gld_lds16(const unsigned short* g,
                                                 unsigned short* l) {
  __builtin_amdgcn_global_load_lds(
      (const __attribute__((address_space(1))) unsigned int*)g,
      (__attribute__((address_space(3))) unsigned int*)l,
      16, 0, 0);
}

__global__ __launch_bounds__(256) void gemm_kernel(
    const unsigned short* __restrict__ A,    // [1600][768] bf16 (pooled)
    const unsigned short* __restrict__ Bw,   // [768][768]  bf16 (conv_w)
    const float* __restrict__ bias,          // [768]
    float* __restrict__ outp)                // [1600][768] f32
{
  __shared__ __align__(16) unsigned short As[2][BM * BK];   // 2 x 8 KB
  __shared__ __align__(16) unsigned short Bs[2][BM * BK];   // 2 x 8 KB

  const int tid = threadIdx.x;
  const int w = tid >> 6;           // wave 0..3
  const int l = tid & 63;           // lane
  const int bm = blockIdx.x * BM;
  const int bn = blockIdx.y * BN;

  const int wr = w >> 1, wc = w & 1;
  const int lr = l & 15;
  const int kh = l >> 4;            // 0..3

  const int rA0 = (wr << 5) + lr;   // A-frag rows (mi=0 / mi=1 = +16)
  const int rB0 = (wc << 5) + lr;   // B-frag rows (= C cols)

#define STAGE(buf, kk)                                                       \
  {                                                                          \
    _Pragma("unroll")                                                        \
    for (int q = 0; q < 2; ++q) {                                            \
      const int s   = (q << 8) + tid;                                        \
      const int row = s >> 3;                                                \
      const int c16 = (s & 7) ^ (row & 7);                                   \
      gld_lds16(A  + (size_t)(bm + row) * NK + (kk) + (c16 << 3),            \
                &As[buf][s << 3]);                                           \
      gld_lds16(Bw + (size_t)(bn + row) * NK + (kk) + (c16 << 3),            \
                &Bs[buf][s << 3]);                                           \
    }                                                                        \
  }

  f32x4 acc[2][2] = {};

  STAGE(0, 0)
  __syncthreads();                  // drains vmcnt(0)

  int cur = 0;
  for (int it = 0; it < NK / BK; ++it) {
    if (it + 1 < NK / BK) STAGE(cur ^ 1, (it + 1) * BK)   // overlap w/ compute

#pragma unroll
    for (int ks = 0; ks < 2; ++ks) {
      const int kq = (ks << 2) + kh;                      // k/8 quad index
      const bf16x8 a0 = *reinterpret_cast<const bf16x8*>(
          &As[cur][(rA0 << 6) + ((kq ^ (rA0 & 7)) << 3)]);
      const bf16x8 a1 = *reinterpret_cast<const bf16x8*>(
          &As[cur][((rA0 + 16) << 6) + ((kq ^ (rA0 & 7)) << 3)]);
      const bf16x8 b0 = *reinterpret_cast<const bf16x8*>(
          &Bs[cur][(rB0 << 6) + ((kq ^ (rB0 & 7)) << 3)]);
      const bf16x8 b1 = *reinterpret_cast<const bf16x8*>(
          &Bs[cur][((rB0 + 16) << 6) + ((kq ^ (rB0 & 7)) << 3)]);
      acc[0][0] = __builtin_amdgcn_mfma_f32_16x16x32_bf16(a0, b0, acc[0][0], 0, 0, 0);
      acc[0][1] = __builtin_amdgcn_mfma_f32_16x16x32_bf16(a0, b1, acc[0][1], 0, 0, 0);
      acc[1][0] = __builtin_amdgcn_mfma_f32_16x16x32_bf16(a1, b0, acc[1][0], 0, 0, 0);
      acc[1][1] = __builtin_amdgcn_mfma_f32_16x16x32_bf16(a1, b1, acc[1][1], 0, 0, 0);
    }

    __syncthreads();                // drains vmcnt (next tile landed) + LDS reuse
    cur ^= 1;
  }
#undef STAGE

  // Epilogue: C/D layout col = lane&15, row = (lane>>4)*4 + reg
#pragma unroll
  for (int ni = 0; ni < 2; ++ni) {
    const int col = bn + (wc << 5) + (ni << 4) + lr;
    const float bv = bias[col];
#pragma unroll
    for (int mi = 0; mi < 2; ++mi) {
      const int rbase = bm + (wr << 5) + (mi << 4) + (kh << 2);
#pragma unroll
      for (int q = 0; q < 4; ++q) {
        outp[(size_t)(rbase + q) * ND + col] = acc[mi][ni][q] + bv;
      }
    }
  }
}

extern "C" void kernel_launch(void* const* d_in, const int* in_sizes, int n_in,
                              void* d_out, int out_size, void* d_ws, size_t ws_size,
                              hipStream_t stream) {
  (void)in_sizes; (void)n_in; (void)out_size; (void)ws_size;
  const float* features  = (const float*)d_in[0];
  const float* keypoints = (const float*)d_in[1];
  const float* conv_w    = (const float*)d_in[2];
  const float* conv_b    = (const float*)d_in[3];
  float* outp = (float*)d_out;

  unsigned short* pooled = (unsigned short*)d_ws;                    // 2,457,600 B
  unsigned short* wbf    = (unsigned short*)((char*)d_ws + 2457600); // 1,179,648 B

  pool_convw_kernel<<<NCVW + NTASK, 256, 0, stream>>>(features, keypoints,
                                                      conv_w, pooled, wbf);

  dim3 grid(NKP / BM, ND / BN);   // 25 x 12 = 300
  gemm_kernel<<<grid, 256, 0, stream>>>(pooled, wbf, conv_b, outp);
}

// Round 7
// 38.739 us; speedup vs baseline: 2.0975x; 2.0975x over previous
//
#include <hip/hip_runtime.h>

// Problem constants (match reference)
#define NB 8
#define NT 8
#define NO 25
#define NC 3
#define NH 192
#define NW 640
#define NP 16
#define ND 768
#define NGH 12
#define NGW 2
#define NKP (NB*NT*NO)   // 1600 keypoints
#define NK (NC*NP*NP)    // 768 (GEMM K)
#define NTASK (NKP*NC)   // 4800 pool tasks
#define NCVW ((NK*ND)/(256*4))  // 576 convw blocks (float4 per thread)

#define S_STRIDE 41      // odd stride: breaks even-bank stripes on sampling reads

typedef __attribute__((ext_vector_type(4))) float  f32x4;
typedef __attribute__((ext_vector_type(8))) short  bf16x8;

static __device__ __forceinline__ unsigned short f2bf(float f) {
  union { float f; unsigned u; } x; x.f = f;
  unsigned r = x.u + 0x7FFFu + ((x.u >> 16) & 1u);   // round-to-nearest-even
  return (unsigned short)(r >> 16);
}

// ---------------------------------------------------------------------------
// Kernel 1 (fused): blocks [0,NCVW) convert conv_w f32->bf16;
// blocks [NCVW, NCVW+NTASK) do ROI-align pooling, one per (keypoint,channel).
// Sampling is BRANCH-FREE: all 12x2 sample groups issued unconditionally with
// zero weights for invalid ones, so the ~48 ds_read2_b32 batch-issue instead
// of serializing one LDS round-trip per unrolled iteration.
// ---------------------------------------------------------------------------
__global__ __launch_bounds__(256) void pool_convw_kernel(
    const float* __restrict__ features,   // [B][C][T][H][W] f32
    const float* __restrict__ keypoints,  // [N][3] (kx, ky, kr)
    const float* __restrict__ conv_w,     // [768][768] f32
    unsigned short* __restrict__ pooled,  // [N][768] bf16
    unsigned short* __restrict__ wbf)     // [768][768] bf16
{
  __shared__ float S[NH * S_STRIDE + 8];  // +8 guard for weight-0 clamped reads

  const int bid = blockIdx.x;
  const int tid = threadIdx.x;

  if (bid < NCVW) {                       // ---- conv_w convert path ----
    const int i = bid * 256 + tid;        // float4 index
    const float4 v = reinterpret_cast<const float4*>(conv_w)[i];
    ushort4 o;
    o.x = f2bf(v.x); o.y = f2bf(v.y); o.z = f2bf(v.z); o.w = f2bf(v.w);
    reinterpret_cast<ushort4*>(wbf)[i] = o;
    return;                               // no barrier on this path (block-uniform)
  }

  // ---- pooling path ----
  // XCD-chunked swizzle over 4800 tasks (4800 = 8*600; NCVW = 576 = 72*8
  // keeps the blockIdx->XCD phase aligned)
  const int rb = bid - NCVW;
  const int t  = (rb & 7) * (NTASK / 8) + (rb >> 3);
  const int n  = t / 3;
  const int ch = t - 3 * n;

  const float kx = keypoints[n * 3 + 0];
  const float ky = keypoints[n * 3 + 1];
  const float kr = keypoints[n * 3 + 2];

  // Boxes exactly as reference (by2 uses kx — reference quirk, keep it)
  const float bx1 = fmaxf(kx - kr, 0.0f);
  const float by1 = fmaxf(ky - kr, 0.0f);
  const float bx2 = fminf(kx + kr, (float)NW);
  const float by2 = fminf(kx + kr, (float)NH);

  const float start_h = by1 - 0.5f;
  const float start_w = bx1 - 0.5f;
  const float bin_h = (by2 - by1) * (1.0f / (float)NP);
  const float bin_w = (bx2 - bx1) * (1.0f / (float)NP);
  const int gh = (int)ceilf(bin_h);       // == ceil(roi_h / P), 1..12
  const int gw = (int)ceilf(bin_w);       // 1..2
  const float ghf = (float)max(gh, 1);
  const float gwf = (float)max(gw, 1);
  const float inv_count = 1.0f / (float)max(gh * gw, 1);
  const float sub_h = bin_h / ghf;        // sub-sample spacing
  const float sub_w = bin_w / gwf;

  // --- footprint extent (block-uniform; samples monotonic in bin,g) ---
  const float cy_min = start_h + 0.5f * sub_h;
  const float cy_max = start_h + 15.0f * bin_h + ((float)(gh - 1) + 0.5f) * sub_h;
  const float cx_min = start_w + 0.5f * sub_w;
  const float cx_max = start_w + 15.0f * bin_w + ((float)(gw - 1) + 0.5f) * sub_w;
  const int rmin = (int)floorf(fminf(fmaxf(cy_min, 0.0f), (float)(NH - 1)));
  const int rmax = min((int)floorf(fminf(fmaxf(cy_max, 0.0f), (float)(NH - 1))) + 1, NH - 1);
  const int cmin = (int)floorf(fminf(fmaxf(cx_min, 0.0f), (float)(NW - 1)));
  const int cmax = min((int)floorf(fminf(fmaxf(cx_max, 0.0f), (float)(NW - 1))) + 1, NW - 1);
  const int nrows = rmax - rmin + 1;          // <= 192
  const int cmin_al = cmin & ~3;              // 4-aligned for float4 loads
  const int nq = ((cmax - cmin_al) >> 2) + 1; // float4 groups per row, <= 10
  const int tot = nrows * nq;                 // <= 1920
  const float inv_nq = 1.0f / (float)nq;

  const int img  = n / NO;                    // b*T + t
  const int bb   = img / NT;
  const int timg = img - bb * NT;
  const float* __restrict__ src =
      features + (size_t)((bb * NC + ch) * NT + timg) * (NH * NW);

  // --- register staging: up to 8 predicated float4 loads, all independent ---
  float4 v0, v1, v2, v3, v4, v5, v6, v7;
  int ro0, ro1, ro2, ro3, ro4, ro5, ro6, ro7;   // LDS float offset, -1 = skip

#define STAGE_LOAD(Q, V, RO)                                                 \
  {                                                                          \
    const int e = tid + (Q << 8);                                            \
    if (e < tot) {                                                           \
      const int r  = (int)(((float)e + 0.5f) * inv_nq);                      \
      const int c4 = (e - r * nq) << 2;                                      \
      const int gc = cmin_al + c4;                                           \
      const float* p = src + (size_t)(rmin + r) * NW + gc;                   \
      if (gc + 3 < NW) { V = *reinterpret_cast<const float4*>(p); }          \
      else { V.x = p[0]; V.y = p[min(1, NW - 1 - gc)];                       \
             V.z = p[min(2, NW - 1 - gc)]; V.w = p[min(3, NW - 1 - gc)]; }   \
      RO = r * S_STRIDE + c4;                                                \
    } else { RO = -1; }                                                      \
  }

  STAGE_LOAD(0, v0, ro0) STAGE_LOAD(1, v1, ro1) STAGE_LOAD(2, v2, ro2)
  STAGE_LOAD(3, v3, ro3) STAGE_LOAD(4, v4, ro4) STAGE_LOAD(5, v5, ro5)
  STAGE_LOAD(6, v6, ro6) STAGE_LOAD(7, v7, ro7)
#undef STAGE_LOAD

#define STAGE_WRITE(V, RO)                                                   \
  if (RO >= 0) { float* s = &S[RO];                                          \
    s[0] = V.x; s[1] = V.y; s[2] = V.z; s[3] = V.w; }

  STAGE_WRITE(v0, ro0) STAGE_WRITE(v1, ro1) STAGE_WRITE(v2, ro2)
  STAGE_WRITE(v3, ro3) STAGE_WRITE(v4, ro4) STAGE_WRITE(v5, ro5)
  STAGE_WRITE(v6, ro6) STAGE_WRITE(v7, ro7)
#undef STAGE_WRITE

  // zero pad column (first column beyond staged region): x0+1 / clamped reads
  // hit it only with weight 0 — keep it finite, not stale-LDS bits.
  if (tid < nrows) S[tid * S_STRIDE + (nq << 2)] = 0.0f;

  __syncthreads();

  // --- branch-free bilinear sampling (reference formula order) ---
  const int i = tid >> 4;
  const int j = tid & 15;

  float hxv[NGW], lxv[NGW]; int cxv[NGW];
#pragma unroll
  for (int gx = 0; gx < NGW; ++gx) {
    const float c = start_w + (float)j * bin_w + ((float)gx + 0.5f) * sub_w;
    const float cc = fminf(fmaxf(c, 0.0f), (float)(NW - 1));
    const int x0 = (int)floorf(cc);
    const float lx = cc - (float)x0;
    const bool vx = gx < gw;
    lxv[gx] = vx ? lx : 0.0f;
    hxv[gx] = vx ? 1.0f - lx : 0.0f;
    cxv[gx] = min(x0 - cmin_al, nq << 2);   // in-bounds even for invalid gx
  }

  float acc = 0.0f;
#pragma unroll
  for (int gy = 0; gy < NGH; ++gy) {
    const float c = start_h + (float)i * bin_h + ((float)gy + 0.5f) * sub_h;
    const float cc = fminf(fmaxf(c, 0.0f), (float)(NH - 1));
    const int y0 = (int)floorf(cc);
    const float ly = cc - (float)y0;
    const bool vy = gy < gh;
    const float wl = vy ? ly : 0.0f;        // weight-zeroed instead of break
    const float wh = vy ? 1.0f - ly : 0.0f;
    const int r0  = min(y0 - rmin, nrows - 1);   // y0 >= rmin by monotonicity
    const int ry0 = r0 * S_STRIDE;
    const int ry1 = min(r0 + 1, nrows - 1) * S_STRIDE;
#pragma unroll
    for (int gx = 0; gx < NGW; ++gx) {
      const float* p0 = &S[ry0 + cxv[gx]];
      const float* p1 = &S[ry1 + cxv[gx]];
      const float s00 = p0[0], s01 = p0[1];   // -> ds_read2_b32
      const float s10 = p1[0], s11 = p1[1];   // -> ds_read2_b32
      acc += wh * (hxv[gx] * s00 + lxv[gx] * s01)
           + wl * (hxv[gx] * s10 + lxv[gx] * s11);
    }
  }
  pooled[(size_t)n * NK + ch * (NP * NP) + tid] = f2bf(acc * inv_count);
}

// ---------------------------------------------------------------------------
// Kernel 2: bf16 MFMA GEMM  out[1600][768] = A[1600][768] . Bw[768][768]^T + b
// BM=BN=64, BK=64, grid 25x12=300 blocks, 4 waves (2x2), wave tile 32x32.
// Double-buffered LDS, 2-phase prefetch, XOR-swizzle via pre-swizzled source.
// (identical to round 4)
// ---------------------------------------------------------------------------
#define BM 64
#define BN 64
#define BK 64

static __device__ __forceinline__ void gld_lds16(const unsigned short* g,
                                                 unsigned short* l) {
  __builtin_amdgcn_global_load_lds(
      (const __attribute__((address_space(1))) unsigned int*)g,
      (__attribute__((address_space(3))) unsigned int*)l,
      16, 0, 0);
}

__global__ __launch_bounds__(256) void gemm_kernel(
    const unsigned short* __restrict__ A,    // [1600][768] bf16 (pooled)
    const unsigned short* __restrict__ Bw,   // [768][768]  bf16 (conv_w)
    const float* __restrict__ bias,          // [768]
    float* __restrict__ outp)                // [1600][768] f32
{
  __shared__ __align__(16) unsigned short As[2][BM * BK];   // 2 x 8 KB
  __shared__ __align__(16) unsigned short Bs[2][BM * BK];   // 2 x 8 KB

  const int tid = threadIdx.x;
  const int w = tid >> 6;           // wave 0..3
  const int l = tid & 63;           // lane
  const int bm = blockIdx.x * BM;
  const int bn = blockIdx.y * BN;

  const int wr = w >> 1, wc = w & 1;
  const int lr = l & 15;
  const int kh = l >> 4;            // 0..3

  const int rA0 = (wr << 5) + lr;   // A-frag rows (mi=0 / mi=1 = +16)
  const int rB0 = (wc << 5) + lr;   // B-frag rows (= C cols)

#define STAGE(buf, kk)                                                       \
  {                                                                          \
    _Pragma("unroll")                                                        \
    for (int q = 0; q < 2; ++q) {                                            \
      const int s   = (q << 8) + tid;                                        \
      const int row = s >> 3;                                                \
      const int c16 = (s & 7) ^ (row & 7);                                   \
      gld_lds16(A  + (size_t)(bm + row) * NK + (kk) + (c16 << 3),            \
                &As[buf][s << 3]);                                           \
      gld_lds16(Bw + (size_t)(bn + row) * NK + (kk) + (c16 << 3),            \
                &Bs[buf][s << 3]);                                           \
    }                                                                        \
  }

  f32x4 acc[2][2] = {};

  STAGE(0, 0)
  __syncthreads();                  // drains vmcnt(0)

  int cur = 0;
  for (int it = 0; it < NK / BK; ++it) {
    if (it + 1 < NK / BK) STAGE(cur ^ 1, (it + 1) * BK)   // overlap w/ compute

#pragma unroll
    for (int ks = 0; ks < 2; ++ks) {
      const int kq = (ks << 2) + kh;                      // k/8 quad index
      const bf16x8 a0 = *reinterpret_cast<const bf16x8*>(
          &As[cur][(rA0 << 6) + ((kq ^ (rA0 & 7)) << 3)]);
      const bf16x8 a1 = *reinterpret_cast<const bf16x8*>(
          &As[cur][((rA0 + 16) << 6) + ((kq ^ (rA0 & 7)) << 3)]);
      const bf16x8 b0 = *reinterpret_cast<const bf16x8*>(
          &Bs[cur][(rB0 << 6) + ((kq ^ (rB0 & 7)) << 3)]);
      const bf16x8 b1 = *reinterpret_cast<const bf16x8*>(
          &Bs[cur][((rB0 + 16) << 6) + ((kq ^ (rB0 & 7)) << 3)]);
      acc[0][0] = __builtin_amdgcn_mfma_f32_16x16x32_bf16(a0, b0, acc[0][0], 0, 0, 0);
      acc[0][1] = __builtin_amdgcn_mfma_f32_16x16x32_bf16(a0, b1, acc[0][1], 0, 0, 0);
      acc[1][0] = __builtin_amdgcn_mfma_f32_16x16x32_bf16(a1, b0, acc[1][0], 0, 0, 0);
      acc[1][1] = __builtin_amdgcn_mfma_f32_16x16x32_bf16(a1, b1, acc[1][1], 0, 0, 0);
    }

    __syncthreads();                // drains vmcnt (next tile landed) + LDS reuse
    cur ^= 1;
  }
#undef STAGE

  // Epilogue: C/D layout col = lane&15, row = (lane>>4)*4 + reg
#pragma unroll
  for (int ni = 0; ni < 2; ++ni) {
    const int col = bn + (wc << 5) + (ni << 4) + lr;
    const float bv = bias[col];
#pragma unroll
    for (int mi = 0; mi < 2; ++mi) {
      const int rbase = bm + (wr << 5) + (mi << 4) + (kh << 2);
#pragma unroll
      for (int q = 0; q < 4; ++q) {
        outp[(size_t)(rbase + q) * ND + col] = acc[mi][ni][q] + bv;
      }
    }
  }
}

extern "C" void kernel_launch(void* const* d_in, const int* in_sizes, int n_in,
                              void* d_out, int out_size, void* d_ws, size_t ws_size,
                              hipStream_t stream) {
  (void)in_sizes; (void)n_in; (void)out_size; (void)ws_size;
  const float* features  = (const float*)d_in[0];
  const float* keypoints = (const float*)d_in[1];
  const float* conv_w    = (const float*)d_in[2];
  const float* conv_b    = (const float*)d_in[3];
  float* outp = (float*)d_out;

  unsigned short* pooled = (unsigned short*)d_ws;                    // 2,457,600 B
  unsigned short* wbf    = (unsigned short*)((char*)d_ws + 2457600); // 1,179,648 B

  pool_convw_kernel<<<NCVW + NTASK, 256, 0, stream>>>(features, keypoints,
                                                      conv_w, pooled, wbf);

  dim3 grid(NKP / BM, ND / BN);   // 25 x 12 = 300
  gemm_kernel<<<grid, 256, 0, stream>>>(pooled, wbf, conv_b, outp);
}